// Round 9
// baseline (604.645 us; speedup 1.0000x reference)
//
#include <hip/hip_runtime.h>
#include <hip/hip_bf16.h>
#include <math.h>

#define S_LEN 2048
#define HID 2560
#define NH 8
#define NKV 4
#define HD 256
#define WINDOW 1024

typedef short short8 __attribute__((ext_vector_type(8)));
typedef short short4_t __attribute__((ext_vector_type(4)));
typedef float f32x4 __attribute__((ext_vector_type(4)));
typedef float float4_t __attribute__((ext_vector_type(4)));

__device__ __forceinline__ short bf16_rne(float x) {
  unsigned u = __float_as_uint(x);
  return (short)((u + 0x7FFFu + ((u >> 16) & 1u)) >> 16);
}
__device__ __forceinline__ void split2(float x, short &h, short &l) {
  unsigned u = __float_as_uint(x);
  unsigned hb = (u + 0x7FFFu + ((u >> 16) & 1u)) & 0xFFFF0000u;
  h = (short)(hb >> 16);
  float r = x - __uint_as_float(hb);
  l = bf16_rne(r);
}

// ================= pre-split GEMM, product count by MODE =================
// MODE bit0: + Al*Bh (A split).  bit1: + Ah*Bl (B split).  Always Ah*Bh.
// A [*][K] hi/lo bf16 row-major; B [*][K] hi/lo bf16 (pre-transposed).
// C fp32, leading dim ldc. Tile 64(M)x128(N)x64(K), 256 thr / 4 waves.
#define SWZ(g, r) ((((g) ^ ((r) & 7))) * 8)
template <int MODE>
__global__ __launch_bounds__(256, 3)
void gemm_presplit(const short* __restrict__ Ah, const short* __restrict__ Al,
                   const short* __restrict__ Bh, const short* __restrict__ Bl,
                   float* __restrict__ C, int K, int ldc) {
  constexpr bool USE_AL = (MODE & 1) != 0;
  constexpr bool USE_BL = (MODE & 2) != 0;
  __shared__ short Ahs[64][64];
  __shared__ short Als[USE_AL ? 64 : 1][64];
  __shared__ short Bhs[128][64];
  __shared__ short Bls[USE_BL ? 128 : 1][64];
  const int tid = threadIdx.x;
  const int wv = tid >> 6, lane = tid & 63;
  const int wm = (wv >> 1) * 32, wn = (wv & 1) * 64;
  const int quad = lane >> 4, col = lane & 15;
  const int m0 = blockIdx.y * 64, n0 = blockIdx.x * 128;
  const int srow = tid >> 2, sg = tid & 3;

  f32x4 acc[2][4];
#pragma unroll
  for (int i = 0; i < 2; i++)
#pragma unroll
    for (int j = 0; j < 4; j++) acc[i][j] = (f32x4){0.f, 0.f, 0.f, 0.f};

  for (int k0 = 0; k0 < K; k0 += 64) {
#pragma unroll
    for (int gg = 0; gg < 2; gg++) {
      int g = sg + gg * 4;
      size_t go = (size_t)(m0 + srow) * K + k0 + g * 8;
      *reinterpret_cast<short8*>(&Ahs[srow][SWZ(g, srow)]) =
          *reinterpret_cast<const short8*>(Ah + go);
      if (USE_AL)
        *reinterpret_cast<short8*>(&Als[srow][SWZ(g, srow)]) =
            *reinterpret_cast<const short8*>(Al + go);
    }
#pragma unroll
    for (int rr = 0; rr < 2; rr++) {
      int row = srow + rr * 64;
#pragma unroll
      for (int gg = 0; gg < 2; gg++) {
        int g = sg + gg * 4;
        size_t go = (size_t)(n0 + row) * K + k0 + g * 8;
        *reinterpret_cast<short8*>(&Bhs[row][SWZ(g, row)]) =
            *reinterpret_cast<const short8*>(Bh + go);
        if (USE_BL)
          *reinterpret_cast<short8*>(&Bls[row][SWZ(g, row)]) =
              *reinterpret_cast<const short8*>(Bl + go);
      }
    }
    __syncthreads();
#pragma unroll
    for (int ks = 0; ks < 2; ks++) {
      const int g = ks * 4 + quad;
      short8 afh[2], afl[2], bfh[4], bfl[4];
#pragma unroll
      for (int i = 0; i < 2; i++) {
        int ar = wm + i * 16 + col;
        afh[i] = *reinterpret_cast<const short8*>(&Ahs[ar][SWZ(g, ar)]);
        if (USE_AL)
          afl[i] = *reinterpret_cast<const short8*>(&Als[ar][SWZ(g, ar)]);
      }
#pragma unroll
      for (int j = 0; j < 4; j++) {
        int br = wn + j * 16 + col;
        bfh[j] = *reinterpret_cast<const short8*>(&Bhs[br][SWZ(g, br)]);
        if (USE_BL)
          bfl[j] = *reinterpret_cast<const short8*>(&Bls[br][SWZ(g, br)]);
      }
#pragma unroll
      for (int i = 0; i < 2; i++)
#pragma unroll
        for (int j = 0; j < 4; j++) {
          acc[i][j] = __builtin_amdgcn_mfma_f32_16x16x32_bf16(afh[i], bfh[j], acc[i][j], 0, 0, 0);
          if (USE_BL)
            acc[i][j] = __builtin_amdgcn_mfma_f32_16x16x32_bf16(afh[i], bfl[j], acc[i][j], 0, 0, 0);
          if (USE_AL)
            acc[i][j] = __builtin_amdgcn_mfma_f32_16x16x32_bf16(afl[i], bfh[j], acc[i][j], 0, 0, 0);
        }
    }
    __syncthreads();
  }
#pragma unroll
  for (int i = 0; i < 2; i++)
#pragma unroll
    for (int j = 0; j < 4; j++)
#pragma unroll
      for (int r = 0; r < 4; r++)
        C[(size_t)(m0 + wm + i * 16 + quad * 4 + r) * ldc + n0 + wn + j * 16 + col] =
            acc[i][j][r];
}

// elementwise fp32 -> bf16 hi/lo (for hs)
__global__ __launch_bounds__(256)
void split_kernel(const float* __restrict__ in, short* __restrict__ oh,
                  short* __restrict__ ol, int n4) {
  int i = blockIdx.x * 256 + threadIdx.x;
  if (i >= n4) return;
  float4_t v = reinterpret_cast<const float4_t*>(in)[i];
  short4_t h, l;
#pragma unroll
  for (int e = 0; e < 4; e++) {
    short hh, ll;
    split2(v[e], hh, ll);
    h[e] = hh; l[e] = ll;
  }
  reinterpret_cast<short4_t*>(oh)[i] = h;
  reinterpret_cast<short4_t*>(ol)[i] = l;
}

// W fp32 [KW][NW] -> WT hi/lo bf16 rows (n_ofs+n)[KW], coalesced 128B writes
__global__ __launch_bounds__(256)
void wsplitT_kernel(const float* __restrict__ W, short* __restrict__ WTh,
                    short* __restrict__ WTl, int KW, int NW, int n_ofs) {
  __shared__ float T[64][65];
  const int k0 = blockIdx.x * 64, n0 = blockIdx.y * 64;
  const int tid = threadIdx.x;
  const int r = tid >> 4, c4 = (tid & 15) * 4;
#pragma unroll
  for (int p = 0; p < 4; p++) {
    float4_t v = *reinterpret_cast<const float4_t*>(
        &W[(size_t)(k0 + r + p * 16) * NW + n0 + c4]);
#pragma unroll
    for (int e = 0; e < 4; e++) T[r + p * 16][c4 + e] = v[e];
  }
  __syncthreads();
  const int gk = tid & 7;  // k-granule within row (8 shorts)
#pragma unroll
  for (int pass = 0; pass < 2; pass++) {
    const int n_loc = (tid >> 3) + pass * 32;
    short8 hv, lv;
#pragma unroll
    for (int e = 0; e < 8; e++) {
      short hh, ll;
      split2(T[gk * 8 + e][n_loc], hh, ll);
      hv[e] = hh; lv[e] = ll;
    }
    size_t base = (size_t)(n_ofs + n0 + n_loc) * KW + k0 + gk * 8;
    *reinterpret_cast<short8*>(WTh + base) = hv;
    *reinterpret_cast<short8*>(WTl + base) = lv;
  }
}

// ================= norms (stride-parametrized, proven) =================
__global__ __launch_bounds__(256)
void qnorm_kernel(float* __restrict__ io, int rs, const float* __restrict__ w,
                  const float* __restrict__ cosb, const float* __restrict__ sinb) {
  const int sq = blockIdx.x / NH;
  const int h = blockIdx.x % NH;
  const int d = threadIdx.x;
  const size_t idx = (size_t)sq * rs + h * HD + d;
  float x = io[idx];
  float v = x * x;
#pragma unroll
  for (int off = 32; off; off >>= 1) v += __shfl_down(v, off);
  __shared__ float red[4];
  __shared__ float sscale;
  __shared__ float nb[HD];
  if ((d & 63) == 0) red[d >> 6] = v;
  __syncthreads();
  if (d == 0)
    sscale = rsqrtf((red[0] + red[1] + red[2] + red[3]) * (1.0f / HD) + 1e-6f);
  __syncthreads();
  float n = x * sscale * w[d];
  nb[d] = n;
  __syncthreads();
  float other = (d < HD / 2) ? -nb[d + HD / 2] : nb[d - HD / 2];
  io[idx] = n * cosb[(size_t)sq * HD + d] + other * sinb[(size_t)sq * HD + d];
}

__global__ __launch_bounds__(256)
void knorm_split_kernel(const float* __restrict__ in, int rs,
                        short* __restrict__ kh, short* __restrict__ kl,
                        const float* __restrict__ w, const float* __restrict__ cosb,
                        const float* __restrict__ sinb) {
  const int sq = blockIdx.x / NKV;
  const int h = blockIdx.x % NKV;
  const int d = threadIdx.x;
  float x = in[(size_t)sq * rs + h * HD + d];
  float v = x * x;
#pragma unroll
  for (int off = 32; off; off >>= 1) v += __shfl_down(v, off);
  __shared__ float red[4];
  __shared__ float sscale;
  __shared__ float nb[HD];
  if ((d & 63) == 0) red[d >> 6] = v;
  __syncthreads();
  if (d == 0)
    sscale = rsqrtf((red[0] + red[1] + red[2] + red[3]) * (1.0f / HD) + 1e-6f);
  __syncthreads();
  float n = x * sscale * w[d];
  nb[d] = n;
  __syncthreads();
  float other = (d < HD / 2) ? -nb[d + HD / 2] : nb[d - HD / 2];
  n = n * cosb[(size_t)sq * HD + d] + other * sinb[(size_t)sq * HD + d];
  short hh, ll;
  split2(n, hh, ll);
  kh[((size_t)sq * NKV + h) * HD + d] = hh;
  kl[((size_t)sq * NKV + h) * HD + d] = ll;
}

__global__ __launch_bounds__(256)
void vnormT_kernel(const float* __restrict__ in, int rs, short* __restrict__ vtb) {
  const int sq = blockIdx.x / NKV;
  const int h = blockIdx.x % NKV;
  const int d = threadIdx.x;
  float x = in[(size_t)sq * rs + h * HD + d];
  float v = x * x;
#pragma unroll
  for (int off = 32; off; off >>= 1) v += __shfl_down(v, off);
  __shared__ float red[4];
  __shared__ float sscale;
  if ((d & 63) == 0) red[d >> 6] = v;
  __syncthreads();
  if (d == 0)
    sscale = rsqrtf((red[0] + red[1] + red[2] + red[3]) * (1.0f / HD) + 1e-6f);
  __syncthreads();
  vtb[((size_t)h * HD + d) * S_LEN + sq] = bf16_rne(x * sscale);
}

// ================= flash attention (swizzled LDS, 3 blocks/CU) =============
// K granule g(0..31) of row r stored at g^(r&7); V/P granule g(0..3) of row d
// stored at (g+(d>>1))&3. All staging/fragment accesses <=2-way bank aliasing.
#define KSW(g, r) (((g) ^ ((r) & 7)) * 8)
#define VSW(g, d) ((((g) + ((d) >> 1)) & 3) * 8)
__global__ __launch_bounds__(256, 3)
void flash_attn2(const float* __restrict__ qn, int qrs,
                 const short* __restrict__ kh, const short* __restrict__ kl,
                 const short* __restrict__ vtb, float* __restrict__ oA,
                 float* __restrict__ oB, float* __restrict__ mlA,
                 float* __restrict__ mlB) {
  __shared__ short Kh[32][256], Kl[32][256];  // 32 KB
  __shared__ short Vb[256][32];               // 16 KB
  __shared__ short Ps[64][32];                // 4 KB   (total 53248 B)
  const int qt = blockIdx.x, h = blockIdx.y, sp = blockIdx.z;
  const int kvh = h >> 1;
  const int q0 = qt * 64;
  const int tid = threadIdx.x;
  const int w = tid >> 6, lane = tid & 63;
  const int quad = lane >> 4, col = lane & 15;
  float* oOut = sp ? oB : oA;
  float* mlOut = sp ? mlB : mlA;
  short8 qh[8], ql[8];
  {
    const float* qrow = qn + (size_t)(q0 + w * 16 + col) * qrs + h * HD;
#pragma unroll
    for (int s8 = 0; s8 < 8; s8++) {
      int d0 = s8 * 32 + quad * 8;
      float4_t a = *reinterpret_cast<const float4_t*>(qrow + d0);
      float4_t b = *reinterpret_cast<const float4_t*>(qrow + d0 + 4);
#pragma unroll
      for (int e = 0; e < 4; e++) {
        short hh, ll;
        split2(a[e], hh, ll);
        qh[s8][e] = hh; ql[s8][e] = ll;
        split2(b[e], hh, ll);
        qh[s8][4 + e] = hh; ql[s8][4 + e] = ll;
      }
    }
  }
  f32x4 o[16];
#pragma unroll
  for (int i = 0; i < 16; i++) o[i] = (f32x4){0.f, 0.f, 0.f, 0.f};
  float m_r[4] = {-INFINITY, -INFINITY, -INFINITY, -INFINITY};
  float l_r[4] = {0.f, 0.f, 0.f, 0.f};
  const int lo_t = (q0 > 1023) ? ((q0 - 1023) >> 5) : 0;
  const int hi_t = (q0 + 63) >> 5;
  const int halfn = (hi_t - lo_t + 2) >> 1;
  const int t0 = sp ? (lo_t + halfn) : lo_t;
  const int t1 = sp ? hi_t : (lo_t + halfn - 1);
  for (int kt = t0; kt <= t1; kt++) {
    const int kt0 = kt << 5;
    __syncthreads();
#pragma unroll
    for (int i = 0; i < 4; i++) {
      int idx = tid + i * 256;
      int row = idx >> 5, g = idx & 31;
      size_t gofs = ((size_t)(kt0 + row) * NKV + kvh) * HD + g * 8;
      *reinterpret_cast<short8*>(&Kh[row][KSW(g, row)]) =
          *reinterpret_cast<const short8*>(kh + gofs);
      *reinterpret_cast<short8*>(&Kl[row][KSW(g, row)]) =
          *reinterpret_cast<const short8*>(kl + gofs);
    }
#pragma unroll
    for (int i = 0; i < 4; i++) {
      int idx = tid + i * 256;
      int d = idx >> 2, g = idx & 3;
      *reinterpret_cast<short8*>(&Vb[d][VSW(g, d)]) =
          *reinterpret_cast<const short8*>(
              vtb + ((size_t)kvh * HD + d) * S_LEN + kt0 + g * 8);
    }
    __syncthreads();
    f32x4 sc[2];
    sc[0] = (f32x4){0.f, 0.f, 0.f, 0.f};
    sc[1] = (f32x4){0.f, 0.f, 0.f, 0.f};
#pragma unroll
    for (int s8 = 0; s8 < 8; s8++) {
#pragma unroll
      for (int nt = 0; nt < 2; nt++) {
        const int br = nt * 16 + col;
        const short8 bh = *reinterpret_cast<const short8*>(
            &Kh[br][KSW(s8 * 4 + quad, br)]);
        const short8 bl = *reinterpret_cast<const short8*>(
            &Kl[br][KSW(s8 * 4 + quad, br)]);
        sc[nt] = __builtin_amdgcn_mfma_f32_16x16x32_bf16(qh[s8], bh, sc[nt], 0, 0, 0);
        sc[nt] = __builtin_amdgcn_mfma_f32_16x16x32_bf16(qh[s8], bl, sc[nt], 0, 0, 0);
        sc[nt] = __builtin_amdgcn_mfma_f32_16x16x32_bf16(ql[s8], bh, sc[nt], 0, 0, 0);
      }
    }
#pragma unroll
    for (int r = 0; r < 4; r++) {
      const int q_abs = q0 + w * 16 + quad * 4 + r;
      const int prow = w * 16 + quad * 4 + r;
#pragma unroll
      for (int nt = 0; nt < 2; nt++) {
        int k_abs = kt0 + nt * 16 + col;
        bool valid = (k_abs <= q_abs) && (q_abs - k_abs < WINDOW);
        if (!valid) sc[nt][r] = -INFINITY;
      }
      float mx = fmaxf(sc[0][r], sc[1][r]);
      mx = fmaxf(mx, __shfl_xor(mx, 1));
      mx = fmaxf(mx, __shfl_xor(mx, 2));
      mx = fmaxf(mx, __shfl_xor(mx, 4));
      mx = fmaxf(mx, __shfl_xor(mx, 8));
      float mn = fmaxf(m_r[r], mx);
      float alpha = (mn == -INFINITY) ? 1.f : __expf(m_r[r] - mn);
      m_r[r] = mn;
      float rsum = 0.f;
#pragma unroll
      for (int nt = 0; nt < 2; nt++) {
        float s = sc[nt][r];
        float e = (s == -INFINITY) ? 0.f : __expf(s - mn);
        rsum += e;
        int ge = nt * 2 + (col >> 3);
        Ps[prow][VSW(ge, prow) + (col & 7)] = bf16_rne(e);
      }
      rsum += __shfl_xor(rsum, 1);
      rsum += __shfl_xor(rsum, 2);
      rsum += __shfl_xor(rsum, 4);
      rsum += __shfl_xor(rsum, 8);
      l_r[r] = l_r[r] * alpha + rsum;
#pragma unroll
      for (int nt2 = 0; nt2 < 16; nt2++) o[nt2][r] *= alpha;
    }
    __syncthreads();
    {
      const int prow = w * 16 + col;
      const short8 pa = *reinterpret_cast<const short8*>(&Ps[prow][VSW(quad, prow)]);
#pragma unroll
      for (int nt = 0; nt < 16; nt++) {
        const int vr = nt * 16 + col;
        const short8 vb = *reinterpret_cast<const short8*>(&Vb[vr][VSW(quad, vr)]);
        o[nt] = __builtin_amdgcn_mfma_f32_16x16x32_bf16(pa, vb, o[nt], 0, 0, 0);
      }
    }
  }
#pragma unroll
  for (int r = 0; r < 4; r++) {
    const int row = q0 + w * 16 + quad * 4 + r;
    const size_t base = ((size_t)row * NH + h) * HD;
#pragma unroll
    for (int nt = 0; nt < 16; nt++) oOut[base + nt * 16 + col] = o[nt][r];
    if (col == 0) {
      mlOut[((size_t)row * NH + h) * 2] = m_r[r];
      mlOut[((size_t)row * NH + h) * 2 + 1] = l_r[r];
    }
  }
}

// merge the two k-splits -> single-bf16 ctx (out-proj A operand)
__global__ __launch_bounds__(256)
void combine_kernel(const float* __restrict__ oA, const float* __restrict__ oB,
                    const float* __restrict__ mlA, const float* __restrict__ mlB,
                    short* __restrict__ ctxh) {
  const int idx = blockIdx.x;
  const int d = threadIdx.x;
  const float mA = mlA[(size_t)idx * 2], lA = mlA[(size_t)idx * 2 + 1];
  const float mB = mlB[(size_t)idx * 2], lB = mlB[(size_t)idx * 2 + 1];
  const float m = fmaxf(mA, mB);
  const float eA = (mA == -INFINITY) ? 0.f : __expf(mA - m);
  const float eB = (mB == -INFINITY) ? 0.f : __expf(mB - m);
  const float inv = 1.0f / (eA * lA + eB * lB);
  const size_t b = (size_t)idx * HD + d;
  ctxh[b] = bf16_rne((eA * oA[b] + eB * oB[b]) * inv);
}

extern "C" void kernel_launch(void* const* d_in, const int* in_sizes, int n_in,
                              void* d_out, int out_size, void* d_ws, size_t ws_size,
                              hipStream_t stream) {
  const float* hs   = (const float*)d_in[0];
  const float* cosb = (const float*)d_in[1];
  const float* sinb = (const float*)d_in[2];
  const float* wq   = (const float*)d_in[3];
  const float* wk   = (const float*)d_in[4];
  const float* wv   = (const float*)d_in[5];
  const float* wo   = (const float*)d_in[6];
  const float* qw   = (const float*)d_in[7];
  const float* kw   = (const float*)d_in[8];
  dim3 blk(256);

  const size_t szAh   = (size_t)S_LEN * HID * 2;       // 10.49 MB
  const size_t szQKVT = (size_t)4096 * HID * 2;        // 20.97 MB
  const size_t szWoT  = (size_t)HID * 2048 * 2;        // 10.49 MB
  const size_t szCqkv = (size_t)S_LEN * 4096 * 4;      // 33.55 MB
  const size_t szKh   = (size_t)S_LEN * NKV * HD * 2;  // 4.19 MB
  const size_t szMl   = (size_t)S_LEN * NH * 2 * 4;    // 131 KB

  char* p = (char*)d_ws + 256;
  short* Ah    = (short*)p;  p += szAh;    // later: oA fp32 (16.8 MB <= Ah+Al 21 MB)
  short* Al    = (short*)p;  p += szAh;
  short* qkvTh = (short*)p;  p += szQKVT;  // later: ctxh bf16 (8.4 MB)
  short* qkvTl = (short*)p;  p += szQKVT;
  short* woTh  = (short*)p;  p += szWoT;
  short* woTl  = (short*)p;  p += szWoT;
  float* Cqkv  = (float*)p;  p += szCqkv;
  short* kh    = (short*)p;  p += szKh;
  short* kl    = (short*)p;  p += szKh;
  short* vtb   = (short*)p;  p += szKh;
  float* mlA   = (float*)p;  p += szMl;
  float* mlB   = (float*)p;  p += szMl;
  float* oA    = (float*)Ah;      // alias: Ah/Al dead after GEMMs
  float* oB    = (float*)d_out;   // dead until out-proj
  short* ctxh  = qkvTh;           // alias: qkvT dead after qkv GEMM

  // prep: split hs; split+transpose weights (coalesced 128B writes)
  split_kernel<<<(S_LEN * HID / 4 + 255) / 256, blk, 0, stream>>>(
      hs, Ah, Al, S_LEN * HID / 4);
  wsplitT_kernel<<<dim3(HID / 64, 2048 / 64), blk, 0, stream>>>(
      wq, qkvTh, qkvTl, HID, 2048, 0);
  wsplitT_kernel<<<dim3(HID / 64, 1024 / 64), blk, 0, stream>>>(
      wk, qkvTh, qkvTl, HID, 1024, 2048);
  wsplitT_kernel<<<dim3(HID / 64, 1024 / 64), blk, 0, stream>>>(
      wv, qkvTh, qkvTl, HID, 1024, 3072);
  wsplitT_kernel<<<dim3(2048 / 64, HID / 64), blk, 0, stream>>>(
      wo, woTh, woTl, 2048, HID, 0);
  // q|k projection: 3-product (score precision needs it)
  gemm_presplit<3><<<dim3(3072 / 128, S_LEN / 64), blk, 0, stream>>>(
      Ah, Al, qkvTh, qkvTl, Cqkv, HID, 4096);
  // v projection: 2-product (v is bf16-rounded downstream anyway)
  gemm_presplit<2><<<dim3(1024 / 128, S_LEN / 64), blk, 0, stream>>>(
      Ah, Al, qkvTh + (size_t)3072 * HID, qkvTl + (size_t)3072 * HID,
      Cqkv + 3072, HID, 4096);
  // norms (q in place inside Cqkv; k/v from their column slices)
  qnorm_kernel<<<S_LEN * NH, blk, 0, stream>>>(Cqkv, 4096, qw, cosb, sinb);
  knorm_split_kernel<<<S_LEN * NKV, blk, 0, stream>>>(Cqkv + 2048, 4096, kh, kl,
                                                      kw, cosb, sinb);
  vnormT_kernel<<<S_LEN * NKV, blk, 0, stream>>>(Cqkv + 3072, 4096, vtb);
  // flash attention (split-k x2)
  flash_attn2<<<dim3(S_LEN / 64, NH, 2), blk, 0, stream>>>(
      Cqkv, 4096, kh, kl, vtb, oA, oB, mlA, mlB);
  combine_kernel<<<S_LEN * NH, blk, 0, stream>>>(oA, oB, mlA, mlB, ctxh);
  // out projection: ctx-hi (single) x wo-split -> 2-product
  gemm_presplit<2><<<dim3(HID / 128, S_LEN / 64), blk, 0, stream>>>(
      ctxh, ctxh, woTh, woTl, (float*)d_out, 2048, HID);
}

// Round 10
// 492.672 us; speedup vs baseline: 1.2273x; 1.2273x over previous
//
#include <hip/hip_runtime.h>
#include <hip/hip_bf16.h>
#include <math.h>

#define S_LEN 2048
#define HID 2560
#define NH 8
#define NKV 4
#define HD 256
#define WINDOW 1024

typedef short short8 __attribute__((ext_vector_type(8)));
typedef short short4_t __attribute__((ext_vector_type(4)));
typedef float f32x4 __attribute__((ext_vector_type(4)));
typedef float float4_t __attribute__((ext_vector_type(4)));

__device__ __forceinline__ short bf16_rne(float x) {
  unsigned u = __float_as_uint(x);
  return (short)((u + 0x7FFFu + ((u >> 16) & 1u)) >> 16);
}
__device__ __forceinline__ void split2(float x, short &h, short &l) {
  unsigned u = __float_as_uint(x);
  unsigned hb = (u + 0x7FFFu + ((u >> 16) & 1u)) & 0xFFFF0000u;
  h = (short)(hb >> 16);
  float r = x - __uint_as_float(hb);
  l = bf16_rne(r);
}

// ================= pre-split GEMM, product count by MODE =================
// MODE bit0: + Al*Bh (A split).  bit1: + Ah*Bl (B split).  Always Ah*Bh.
// A [*][K] hi/lo bf16 row-major; B [*][K] hi/lo bf16 (pre-transposed).
// C fp32, leading dim ldc. Tile 64(M)x128(N)x64(K), 256 thr / 4 waves.
#define SWZ(g, r) ((((g) ^ ((r) & 7))) * 8)
template <int MODE>
__global__ __launch_bounds__(256, 3)
void gemm_presplit(const short* __restrict__ Ah, const short* __restrict__ Al,
                   const short* __restrict__ Bh, const short* __restrict__ Bl,
                   float* __restrict__ C, int K, int ldc) {
  constexpr bool USE_AL = (MODE & 1) != 0;
  constexpr bool USE_BL = (MODE & 2) != 0;
  __shared__ short Ahs[64][64];
  __shared__ short Als[USE_AL ? 64 : 1][64];
  __shared__ short Bhs[128][64];
  __shared__ short Bls[USE_BL ? 128 : 1][64];
  const int tid = threadIdx.x;
  const int wv = tid >> 6, lane = tid & 63;
  const int wm = (wv >> 1) * 32, wn = (wv & 1) * 64;
  const int quad = lane >> 4, col = lane & 15;
  const int m0 = blockIdx.y * 64, n0 = blockIdx.x * 128;
  const int srow = tid >> 2, sg = tid & 3;

  f32x4 acc[2][4];
#pragma unroll
  for (int i = 0; i < 2; i++)
#pragma unroll
    for (int j = 0; j < 4; j++) acc[i][j] = (f32x4){0.f, 0.f, 0.f, 0.f};

  for (int k0 = 0; k0 < K; k0 += 64) {
#pragma unroll
    for (int gg = 0; gg < 2; gg++) {
      int g = sg + gg * 4;
      size_t go = (size_t)(m0 + srow) * K + k0 + g * 8;
      *reinterpret_cast<short8*>(&Ahs[srow][SWZ(g, srow)]) =
          *reinterpret_cast<const short8*>(Ah + go);
      if (USE_AL)
        *reinterpret_cast<short8*>(&Als[srow][SWZ(g, srow)]) =
            *reinterpret_cast<const short8*>(Al + go);
    }
#pragma unroll
    for (int rr = 0; rr < 2; rr++) {
      int row = srow + rr * 64;
#pragma unroll
      for (int gg = 0; gg < 2; gg++) {
        int g = sg + gg * 4;
        size_t go = (size_t)(n0 + row) * K + k0 + g * 8;
        *reinterpret_cast<short8*>(&Bhs[row][SWZ(g, row)]) =
            *reinterpret_cast<const short8*>(Bh + go);
        if (USE_BL)
          *reinterpret_cast<short8*>(&Bls[row][SWZ(g, row)]) =
              *reinterpret_cast<const short8*>(Bl + go);
      }
    }
    __syncthreads();
#pragma unroll
    for (int ks = 0; ks < 2; ks++) {
      const int g = ks * 4 + quad;
      short8 afh[2], afl[2], bfh[4], bfl[4];
#pragma unroll
      for (int i = 0; i < 2; i++) {
        int ar = wm + i * 16 + col;
        afh[i] = *reinterpret_cast<const short8*>(&Ahs[ar][SWZ(g, ar)]);
        if (USE_AL)
          afl[i] = *reinterpret_cast<const short8*>(&Als[ar][SWZ(g, ar)]);
      }
#pragma unroll
      for (int j = 0; j < 4; j++) {
        int br = wn + j * 16 + col;
        bfh[j] = *reinterpret_cast<const short8*>(&Bhs[br][SWZ(g, br)]);
        if (USE_BL)
          bfl[j] = *reinterpret_cast<const short8*>(&Bls[br][SWZ(g, br)]);
      }
#pragma unroll
      for (int i = 0; i < 2; i++)
#pragma unroll
        for (int j = 0; j < 4; j++) {
          acc[i][j] = __builtin_amdgcn_mfma_f32_16x16x32_bf16(afh[i], bfh[j], acc[i][j], 0, 0, 0);
          if (USE_BL)
            acc[i][j] = __builtin_amdgcn_mfma_f32_16x16x32_bf16(afh[i], bfl[j], acc[i][j], 0, 0, 0);
          if (USE_AL)
            acc[i][j] = __builtin_amdgcn_mfma_f32_16x16x32_bf16(afl[i], bfh[j], acc[i][j], 0, 0, 0);
        }
    }
    __syncthreads();
  }
#pragma unroll
  for (int i = 0; i < 2; i++)
#pragma unroll
    for (int j = 0; j < 4; j++)
#pragma unroll
      for (int r = 0; r < 4; r++)
        C[(size_t)(m0 + wm + i * 16 + quad * 4 + r) * ldc + n0 + wn + j * 16 + col] =
            acc[i][j][r];
}

// elementwise fp32 -> bf16 hi/lo (for hs)
__global__ __launch_bounds__(256)
void split_kernel(const float* __restrict__ in, short* __restrict__ oh,
                  short* __restrict__ ol, int n4) {
  int i = blockIdx.x * 256 + threadIdx.x;
  if (i >= n4) return;
  float4_t v = reinterpret_cast<const float4_t*>(in)[i];
  short4_t h, l;
#pragma unroll
  for (int e = 0; e < 4; e++) {
    short hh, ll;
    split2(v[e], hh, ll);
    h[e] = hh; l[e] = ll;
  }
  reinterpret_cast<short4_t*>(oh)[i] = h;
  reinterpret_cast<short4_t*>(ol)[i] = l;
}

// W fp32 [KW][NW] -> WT hi/lo bf16 rows (n_ofs+n)[KW], coalesced 128B writes
__global__ __launch_bounds__(256)
void wsplitT_kernel(const float* __restrict__ W, short* __restrict__ WTh,
                    short* __restrict__ WTl, int KW, int NW, int n_ofs) {
  __shared__ float T[64][65];
  const int k0 = blockIdx.x * 64, n0 = blockIdx.y * 64;
  const int tid = threadIdx.x;
  const int r = tid >> 4, c4 = (tid & 15) * 4;
#pragma unroll
  for (int p = 0; p < 4; p++) {
    float4_t v = *reinterpret_cast<const float4_t*>(
        &W[(size_t)(k0 + r + p * 16) * NW + n0 + c4]);
#pragma unroll
    for (int e = 0; e < 4; e++) T[r + p * 16][c4 + e] = v[e];
  }
  __syncthreads();
  const int gk = tid & 7;  // k-granule within row (8 shorts)
#pragma unroll
  for (int pass = 0; pass < 2; pass++) {
    const int n_loc = (tid >> 3) + pass * 32;
    short8 hv, lv;
#pragma unroll
    for (int e = 0; e < 8; e++) {
      short hh, ll;
      split2(T[gk * 8 + e][n_loc], hh, ll);
      hv[e] = hh; lv[e] = ll;
    }
    size_t base = (size_t)(n_ofs + n0 + n_loc) * KW + k0 + gk * 8;
    *reinterpret_cast<short8*>(WTh + base) = hv;
    *reinterpret_cast<short8*>(WTl + base) = lv;
  }
}

// ================= norms (stride-parametrized, proven) =================
__global__ __launch_bounds__(256)
void qnorm_kernel(float* __restrict__ io, int rs, const float* __restrict__ w,
                  const float* __restrict__ cosb, const float* __restrict__ sinb) {
  const int sq = blockIdx.x / NH;
  const int h = blockIdx.x % NH;
  const int d = threadIdx.x;
  const size_t idx = (size_t)sq * rs + h * HD + d;
  float x = io[idx];
  float v = x * x;
#pragma unroll
  for (int off = 32; off; off >>= 1) v += __shfl_down(v, off);
  __shared__ float red[4];
  __shared__ float sscale;
  __shared__ float nb[HD];
  if ((d & 63) == 0) red[d >> 6] = v;
  __syncthreads();
  if (d == 0)
    sscale = rsqrtf((red[0] + red[1] + red[2] + red[3]) * (1.0f / HD) + 1e-6f);
  __syncthreads();
  float n = x * sscale * w[d];
  nb[d] = n;
  __syncthreads();
  float other = (d < HD / 2) ? -nb[d + HD / 2] : nb[d - HD / 2];
  io[idx] = n * cosb[(size_t)sq * HD + d] + other * sinb[(size_t)sq * HD + d];
}

__global__ __launch_bounds__(256)
void knorm_split_kernel(const float* __restrict__ in, int rs,
                        short* __restrict__ kh, short* __restrict__ kl,
                        const float* __restrict__ w, const float* __restrict__ cosb,
                        const float* __restrict__ sinb) {
  const int sq = blockIdx.x / NKV;
  const int h = blockIdx.x % NKV;
  const int d = threadIdx.x;
  float x = in[(size_t)sq * rs + h * HD + d];
  float v = x * x;
#pragma unroll
  for (int off = 32; off; off >>= 1) v += __shfl_down(v, off);
  __shared__ float red[4];
  __shared__ float sscale;
  __shared__ float nb[HD];
  if ((d & 63) == 0) red[d >> 6] = v;
  __syncthreads();
  if (d == 0)
    sscale = rsqrtf((red[0] + red[1] + red[2] + red[3]) * (1.0f / HD) + 1e-6f);
  __syncthreads();
  float n = x * sscale * w[d];
  nb[d] = n;
  __syncthreads();
  float other = (d < HD / 2) ? -nb[d + HD / 2] : nb[d - HD / 2];
  n = n * cosb[(size_t)sq * HD + d] + other * sinb[(size_t)sq * HD + d];
  short hh, ll;
  split2(n, hh, ll);
  kh[((size_t)sq * NKV + h) * HD + d] = hh;
  kl[((size_t)sq * NKV + h) * HD + d] = ll;
}

__global__ __launch_bounds__(256)
void vnormT_kernel(const float* __restrict__ in, int rs, short* __restrict__ vtb) {
  const int sq = blockIdx.x / NKV;
  const int h = blockIdx.x % NKV;
  const int d = threadIdx.x;
  float x = in[(size_t)sq * rs + h * HD + d];
  float v = x * x;
#pragma unroll
  for (int off = 32; off; off >>= 1) v += __shfl_down(v, off);
  __shared__ float red[4];
  __shared__ float sscale;
  if ((d & 63) == 0) red[d >> 6] = v;
  __syncthreads();
  if (d == 0)
    sscale = rsqrtf((red[0] + red[1] + red[2] + red[3]) * (1.0f / HD) + 1e-6f);
  __syncthreads();
  vtb[((size_t)h * HD + d) * S_LEN + sq] = bf16_rne(x * sscale);
}

// ================= flash attention (swizzled LDS, 2 blocks/CU) =============
// NOTE (round-9 post-mortem): this kernel NEEDS >=128 VGPR (o[16] f32x4 = 64
// + qh/ql fragments = 64). __launch_bounds__(256,3) forced an 84-VGPR budget
// -> scratch spills (+21 MB WRITE_SIZE, 183 us). Keep (256,2).
#define KSW(g, r) (((g) ^ ((r) & 7)) * 8)
#define VSW(g, d) ((((g) + ((d) >> 1)) & 3) * 8)
__global__ __launch_bounds__(256, 2)
void flash_attn2(const float* __restrict__ qn, int qrs,
                 const short* __restrict__ kh, const short* __restrict__ kl,
                 const short* __restrict__ vtb, float* __restrict__ oA,
                 float* __restrict__ oB, float* __restrict__ mlA,
                 float* __restrict__ mlB) {
  __shared__ short Kh[32][256], Kl[32][256];  // 32 KB
  __shared__ short Vb[256][32];               // 16 KB
  __shared__ short Ps[64][32];                // 4 KB   (total 53248 B)
  const int qt = blockIdx.x, h = blockIdx.y, sp = blockIdx.z;
  const int kvh = h >> 1;
  const int q0 = qt * 64;
  const int tid = threadIdx.x;
  const int w = tid >> 6, lane = tid & 63;
  const int quad = lane >> 4, col = lane & 15;
  float* oOut = sp ? oB : oA;
  float* mlOut = sp ? mlB : mlA;
  short8 qh[8], ql[8];
  {
    const float* qrow = qn + (size_t)(q0 + w * 16 + col) * qrs + h * HD;
#pragma unroll
    for (int s8 = 0; s8 < 8; s8++) {
      int d0 = s8 * 32 + quad * 8;
      float4_t a = *reinterpret_cast<const float4_t*>(qrow + d0);
      float4_t b = *reinterpret_cast<const float4_t*>(qrow + d0 + 4);
#pragma unroll
      for (int e = 0; e < 4; e++) {
        short hh, ll;
        split2(a[e], hh, ll);
        qh[s8][e] = hh; ql[s8][e] = ll;
        split2(b[e], hh, ll);
        qh[s8][4 + e] = hh; ql[s8][4 + e] = ll;
      }
    }
  }
  f32x4 o[16];
#pragma unroll
  for (int i = 0; i < 16; i++) o[i] = (f32x4){0.f, 0.f, 0.f, 0.f};
  float m_r[4] = {-INFINITY, -INFINITY, -INFINITY, -INFINITY};
  float l_r[4] = {0.f, 0.f, 0.f, 0.f};
  const int lo_t = (q0 > 1023) ? ((q0 - 1023) >> 5) : 0;
  const int hi_t = (q0 + 63) >> 5;
  const int halfn = (hi_t - lo_t + 2) >> 1;
  const int t0 = sp ? (lo_t + halfn) : lo_t;
  const int t1 = sp ? hi_t : (lo_t + halfn - 1);
  for (int kt = t0; kt <= t1; kt++) {
    const int kt0 = kt << 5;
    __syncthreads();
#pragma unroll
    for (int i = 0; i < 4; i++) {
      int idx = tid + i * 256;
      int row = idx >> 5, g = idx & 31;
      size_t gofs = ((size_t)(kt0 + row) * NKV + kvh) * HD + g * 8;
      *reinterpret_cast<short8*>(&Kh[row][KSW(g, row)]) =
          *reinterpret_cast<const short8*>(kh + gofs);
      *reinterpret_cast<short8*>(&Kl[row][KSW(g, row)]) =
          *reinterpret_cast<const short8*>(kl + gofs);
    }
#pragma unroll
    for (int i = 0; i < 4; i++) {
      int idx = tid + i * 256;
      int d = idx >> 2, g = idx & 3;
      *reinterpret_cast<short8*>(&Vb[d][VSW(g, d)]) =
          *reinterpret_cast<const short8*>(
              vtb + ((size_t)kvh * HD + d) * S_LEN + kt0 + g * 8);
    }
    __syncthreads();
    f32x4 sc[2];
    sc[0] = (f32x4){0.f, 0.f, 0.f, 0.f};
    sc[1] = (f32x4){0.f, 0.f, 0.f, 0.f};
#pragma unroll
    for (int s8 = 0; s8 < 8; s8++) {
#pragma unroll
      for (int nt = 0; nt < 2; nt++) {
        const int br = nt * 16 + col;
        const short8 bh = *reinterpret_cast<const short8*>(
            &Kh[br][KSW(s8 * 4 + quad, br)]);
        const short8 bl = *reinterpret_cast<const short8*>(
            &Kl[br][KSW(s8 * 4 + quad, br)]);
        sc[nt] = __builtin_amdgcn_mfma_f32_16x16x32_bf16(qh[s8], bh, sc[nt], 0, 0, 0);
        sc[nt] = __builtin_amdgcn_mfma_f32_16x16x32_bf16(qh[s8], bl, sc[nt], 0, 0, 0);
        sc[nt] = __builtin_amdgcn_mfma_f32_16x16x32_bf16(ql[s8], bh, sc[nt], 0, 0, 0);
      }
    }
#pragma unroll
    for (int r = 0; r < 4; r++) {
      const int q_abs = q0 + w * 16 + quad * 4 + r;
      const int prow = w * 16 + quad * 4 + r;
#pragma unroll
      for (int nt = 0; nt < 2; nt++) {
        int k_abs = kt0 + nt * 16 + col;
        bool valid = (k_abs <= q_abs) && (q_abs - k_abs < WINDOW);
        if (!valid) sc[nt][r] = -INFINITY;
      }
      float mx = fmaxf(sc[0][r], sc[1][r]);
      mx = fmaxf(mx, __shfl_xor(mx, 1));
      mx = fmaxf(mx, __shfl_xor(mx, 2));
      mx = fmaxf(mx, __shfl_xor(mx, 4));
      mx = fmaxf(mx, __shfl_xor(mx, 8));
      float mn = fmaxf(m_r[r], mx);
      float alpha = (mn == -INFINITY) ? 1.f : __expf(m_r[r] - mn);
      m_r[r] = mn;
      float rsum = 0.f;
#pragma unroll
      for (int nt = 0; nt < 2; nt++) {
        float s = sc[nt][r];
        float e = (s == -INFINITY) ? 0.f : __expf(s - mn);
        rsum += e;
        int ge = nt * 2 + (col >> 3);
        Ps[prow][VSW(ge, prow) + (col & 7)] = bf16_rne(e);
      }
      rsum += __shfl_xor(rsum, 1);
      rsum += __shfl_xor(rsum, 2);
      rsum += __shfl_xor(rsum, 4);
      rsum += __shfl_xor(rsum, 8);
      l_r[r] = l_r[r] * alpha + rsum;
#pragma unroll
      for (int nt2 = 0; nt2 < 16; nt2++) o[nt2][r] *= alpha;
    }
    __syncthreads();
    {
      const int prow = w * 16 + col;
      const short8 pa = *reinterpret_cast<const short8*>(&Ps[prow][VSW(quad, prow)]);
#pragma unroll
      for (int nt = 0; nt < 16; nt++) {
        const int vr = nt * 16 + col;
        const short8 vb = *reinterpret_cast<const short8*>(&Vb[vr][VSW(quad, vr)]);
        o[nt] = __builtin_amdgcn_mfma_f32_16x16x32_bf16(pa, vb, o[nt], 0, 0, 0);
      }
    }
  }
#pragma unroll
  for (int r = 0; r < 4; r++) {
    const int row = q0 + w * 16 + quad * 4 + r;
    const size_t base = ((size_t)row * NH + h) * HD;
#pragma unroll
    for (int nt = 0; nt < 16; nt++) oOut[base + nt * 16 + col] = o[nt][r];
    if (col == 0) {
      mlOut[((size_t)row * NH + h) * 2] = m_r[r];
      mlOut[((size_t)row * NH + h) * 2 + 1] = l_r[r];
    }
  }
}

// merge the two k-splits -> single-bf16 ctx (out-proj A operand)
__global__ __launch_bounds__(256)
void combine_kernel(const float* __restrict__ oA, const float* __restrict__ oB,
                    const float* __restrict__ mlA, const float* __restrict__ mlB,
                    short* __restrict__ ctxh) {
  const int idx = blockIdx.x;
  const int d = threadIdx.x;
  const float mA = mlA[(size_t)idx * 2], lA = mlA[(size_t)idx * 2 + 1];
  const float mB = mlB[(size_t)idx * 2], lB = mlB[(size_t)idx * 2 + 1];
  const float m = fmaxf(mA, mB);
  const float eA = (mA == -INFINITY) ? 0.f : __expf(mA - m);
  const float eB = (mB == -INFINITY) ? 0.f : __expf(mB - m);
  const float inv = 1.0f / (eA * lA + eB * lB);
  const size_t b = (size_t)idx * HD + d;
  ctxh[b] = bf16_rne((eA * oA[b] + eB * oB[b]) * inv);
}

extern "C" void kernel_launch(void* const* d_in, const int* in_sizes, int n_in,
                              void* d_out, int out_size, void* d_ws, size_t ws_size,
                              hipStream_t stream) {
  const float* hs   = (const float*)d_in[0];
  const float* cosb = (const float*)d_in[1];
  const float* sinb = (const float*)d_in[2];
  const float* wq   = (const float*)d_in[3];
  const float* wk   = (const float*)d_in[4];
  const float* wv   = (const float*)d_in[5];
  const float* wo   = (const float*)d_in[6];
  const float* qw   = (const float*)d_in[7];
  const float* kw   = (const float*)d_in[8];
  dim3 blk(256);

  const size_t szAh   = (size_t)S_LEN * HID * 2;       // 10.49 MB
  const size_t szQKVT = (size_t)4096 * HID * 2;        // 20.97 MB
  const size_t szWoT  = (size_t)HID * 2048 * 2;        // 10.49 MB
  const size_t szCqkv = (size_t)S_LEN * 4096 * 4;      // 33.55 MB
  const size_t szKh   = (size_t)S_LEN * NKV * HD * 2;  // 4.19 MB
  const size_t szMl   = (size_t)S_LEN * NH * 2 * 4;    // 131 KB

  char* p = (char*)d_ws + 256;
  short* Ah    = (short*)p;  p += szAh;    // later: oA fp32 (16.8 MB <= Ah+Al 21 MB)
  short* Al    = (short*)p;  p += szAh;
  short* qkvTh = (short*)p;  p += szQKVT;  // later: ctxh bf16 (8.4 MB)
  short* qkvTl = (short*)p;  p += szQKVT;
  short* woTh  = (short*)p;  p += szWoT;
  short* woTl  = (short*)p;  p += szWoT;
  float* Cqkv  = (float*)p;  p += szCqkv;
  short* kh    = (short*)p;  p += szKh;
  short* kl    = (short*)p;  p += szKh;
  short* vtb   = (short*)p;  p += szKh;
  float* mlA   = (float*)p;  p += szMl;
  float* mlB   = (float*)p;  p += szMl;
  float* oA    = (float*)Ah;      // alias: Ah/Al dead after GEMMs
  float* oB    = (float*)d_out;   // dead until out-proj
  short* ctxh  = qkvTh;           // alias: qkvT dead after qkv GEMM

  // prep: split hs; split+transpose weights (coalesced 128B writes)
  split_kernel<<<(S_LEN * HID / 4 + 255) / 256, blk, 0, stream>>>(
      hs, Ah, Al, S_LEN * HID / 4);
  wsplitT_kernel<<<dim3(HID / 64, 2048 / 64), blk, 0, stream>>>(
      wq, qkvTh, qkvTl, HID, 2048, 0);
  wsplitT_kernel<<<dim3(HID / 64, 1024 / 64), blk, 0, stream>>>(
      wk, qkvTh, qkvTl, HID, 1024, 2048);
  wsplitT_kernel<<<dim3(HID / 64, 1024 / 64), blk, 0, stream>>>(
      wv, qkvTh, qkvTl, HID, 1024, 3072);
  wsplitT_kernel<<<dim3(2048 / 64, HID / 64), blk, 0, stream>>>(
      wo, woTh, woTl, 2048, HID, 0);
  // q|k projection: 3-product (score precision needs it)
  gemm_presplit<3><<<dim3(3072 / 128, S_LEN / 64), blk, 0, stream>>>(
      Ah, Al, qkvTh, qkvTl, Cqkv, HID, 4096);
  // v projection: 2-product (v is bf16-rounded downstream anyway)
  gemm_presplit<2><<<dim3(1024 / 128, S_LEN / 64), blk, 0, stream>>>(
      Ah, Al, qkvTh + (size_t)3072 * HID, qkvTl + (size_t)3072 * HID,
      Cqkv + 3072, HID, 4096);
  // norms (q in place inside Cqkv; k/v from their column slices)
  qnorm_kernel<<<S_LEN * NH, blk, 0, stream>>>(Cqkv, 4096, qw, cosb, sinb);
  knorm_split_kernel<<<S_LEN * NKV, blk, 0, stream>>>(Cqkv + 2048, 4096, kh, kl,
                                                      kw, cosb, sinb);
  vnormT_kernel<<<S_LEN * NKV, blk, 0, stream>>>(Cqkv + 3072, 4096, vtb);
  // flash attention (split-k x2)
  flash_attn2<<<dim3(S_LEN / 64, NH, 2), blk, 0, stream>>>(
      Cqkv, 4096, kh, kl, vtb, oA, oB, mlA, mlB);
  combine_kernel<<<S_LEN * NH, blk, 0, stream>>>(oA, oB, mlA, mlB, ctxh);
  // out projection: ctx-hi (single) x wo-split -> 2-product
  gemm_presplit<2><<<dim3(HID / 128, S_LEN / 64), blk, 0, stream>>>(
      ctxh, ctxh, woTh, woTl, (float*)d_out, 2048, HID);
}